// Round 15
// baseline (175.679 us; speedup 1.0000x reference)
//
#include <hip/hip_runtime.h>

typedef unsigned short u16;
typedef __bf16  bf16x8 __attribute__((ext_vector_type(8)));
typedef float   f32x4  __attribute__((ext_vector_type(4)));
typedef unsigned int   u32x2 __attribute__((ext_vector_type(2)));
typedef unsigned int   u32x4 __attribute__((ext_vector_type(4)));
typedef unsigned short u16x4 __attribute__((ext_vector_type(4)));
typedef unsigned short u16x8 __attribute__((ext_vector_type(8)));

#define BB 2
#define HH 16
#define DD 64
#define SS 2048
#define EE 1024

// scale(1/8) * log2(e) folded into Q at the QKV epilogue -> scores are exp2-ready
#define QSCALE 0.1803368801111244f

// ---------- helpers ----------
static __device__ __forceinline__ u16 f2bf(float f) {
    unsigned int u = __float_as_uint(f);
    u += 0x7FFFu + ((u >> 16) & 1u);          // round-to-nearest-even
    return (u16)(u >> 16);
}

// packed f32x2 -> bf16x2 (RNE), 1 VALU op
static __device__ __forceinline__ unsigned int cvtpk(float lo, float hi) {
    unsigned int r;
    asm("v_cvt_pk_bf16_f32 %0, %1, %2" : "=v"(r) : "v"(lo), "v"(hi));
    return r;
}

union BfCast { u32x4 u; bf16x8 b; };
static __device__ __forceinline__ bf16x8 ldb8(const u16* p) {
    BfCast x; x.u = *(const u32x4*)p; return x.b;
}

// async global->LDS, 16B per lane; GLOBAL addr is PER-LANE, LDS dest = wave-uniform base + lane*16
static __device__ __forceinline__ void gload16(const u16* g, u16* l) {
    __builtin_amdgcn_global_load_lds(
        (const __attribute__((address_space(1))) unsigned int*)g,
        (__attribute__((address_space(3))) unsigned int*)l, 16, 0, 0);
}

// universal fragment-order: matrix [M][1024] -> unit = (m>>4)*32 + (k>>5) (1KB),
// within: (((k>>3)&3)*16 + (m&15))*8 + (k&7); MFMA lane reads lane*8 -> conflict-free.
#define UG (32 * 512)    // unit-group stride: one 16-row m-slab (all 32 k-units)
// K (QK A-operand) per bh plane (131072 u16): unit = (s>>4)*2 + (d>>5)
static __device__ __forceinline__ int kidx(int s, int d) {
    return (((s >> 4) * 2 + (d >> 5)) * 512) + ((((d >> 3) & 3) * 16 + (s & 15)) * 8) + (d & 7);
}
// V (PV A-operand, V^T[d][key]): unit = (key>>5)*4 + (d>>4)   [canonical, round-4/6/9 verified]
static __device__ __forceinline__ int vidx(int key, int d) {
    return (((key >> 5) * 4 + (d >> 4)) * 512) + ((((key >> 3) & 3) * 16 + (d & 15)) * 8) + (key & 7);
}

// ---------- 1. fused prep: conv x->frag  |  transpose Wqkv->frag  |  transpose Wout->frag ----------
__global__ __launch_bounds__(256) void prep_kernel(
    const float* __restrict__ x,    u16* __restrict__ xb,
    const float* __restrict__ Wqkv, u16* __restrict__ wqkvT,
    const float* __restrict__ Wout, u16* __restrict__ woutT)
{
    __shared__ float tile[32][33];
    const int bid = blockIdx.x;
    if (bid < 2048) {
        // conv: x [4096][1024] fp32 -> frag-order bf16
        const int t = bid * 256 + threadIdx.x;
        const int u = t >> 6, w = t & 63;
        const int m = (u >> 5) * 16 + (w & 15);
        const int k = (u & 31) * 32 + (w >> 4) * 8;
        const float* p = x + m * 1024 + k;
        const f32x4 a = *(const f32x4*)p;
        const f32x4 b = *(const f32x4*)(p + 4);
        u16x8 o;
        o[0] = f2bf(a[0]); o[1] = f2bf(a[1]); o[2] = f2bf(a[2]); o[3] = f2bf(a[3]);
        o[4] = f2bf(b[0]); o[5] = f2bf(b[1]); o[6] = f2bf(b[2]); o[7] = f2bf(b[3]);
        *(u16x8*)&xb[u * 512 + w * 8] = o;
        return;
    }
    // transpose W[k][n] fp32 -> frag-order bf16 over [n][k]
    const float* in; u16* out; int C, tb;
    if (bid < 2048 + 3072) { in = Wqkv; out = wqkvT; C = 3072; tb = bid - 2048; }
    else                   { in = Wout; out = woutT; C = 1024; tb = bid - 5120; }
    const int tx = threadIdx.x & 31;
    const int ty = threadIdx.x >> 5;          // 0..7
    const int ct = C >> 5;
    const int bc = tb % ct, br = tb / ct;
    const int c0 = bc * 32, r0 = br * 32;     // r=k, c=n
    #pragma unroll
    for (int i = 0; i < 4; i++)
        tile[ty + i * 8][tx] = in[(r0 + ty + i * 8) * C + c0 + tx];
    __syncthreads();
    #pragma unroll
    for (int i = 0; i < 4; i++) {
        const int n = c0 + ty + i * 8;
        out[((n >> 4) * 32 + (r0 >> 5)) * 512 + (((tx >> 3) & 3) * 16 + (n & 15)) * 8 + (tx & 7)]
            = f2bf(tile[tx][ty + i * 8]);
    }
}

// ---------- 2. QKV GEMM (128x128 tile, BK=64, A-only LDS dbuf + B direct from L2) ----------
// Natural block order: XCD = bid%8 = tn%8 -> 3 B-panels/XCD (768 KB) L2-resident; B reads are
// L2 hits. BK=64 halves the barrier/drain count vs BK=32 (16 iters), 32 MFMA per iteration.
__global__ __launch_bounds__(256) void gemm_qkv_kernel(
    const u16* __restrict__ Af,  // x frag-ordered [4096 x 1024]
    const u16* __restrict__ Bf,  // W_qkv^T frag-ordered [3072 x 1024]
    const float* __restrict__ bias,
    u16* __restrict__ Qb, u16* __restrict__ Kb, u16* __restrict__ Vb)
{
    __shared__ __align__(16) u16 Us[2][16 * 512];   // A-only BK=64: 16 units (16 KB) per buf
    const int lane = threadIdx.x & 63;
    const int wave = threadIdx.x >> 6;
    const int nb = 3 * EE / 128;                // 24
    const int tm = blockIdx.x / nb, tn = blockIdx.x % nb;
    const int lm = lane & 15, quad = lane >> 4;
    const int wy = wave >> 1, wx = wave & 1;    // wave tile 64x64

    // A staging: wave stages units u=4w..4w+3; unit u = slab (u>>1), k-half (u&1)
    const u16* spA[4];
    #pragma unroll
    for (int j = 0; j < 4; j++) {
        const int u = 4 * wave + j;
        spA[j] = Af + (tm * 8 + (u >> 1)) * UG + (u & 1) * 512 + lane * 8;
    }
    // B direct-read pointers: this wave's 4 B-units (L2-resident panel)
    const u16* bp[4];
    #pragma unroll
    for (int i = 0; i < 4; i++) bp[i] = Bf + (tn * 8 + wx * 4 + i) * UG + lane * 8;

    f32x4 acc[4][4] = {};

    #pragma unroll
    for (int j = 0; j < 4; j++) gload16(spA[j], &Us[0][(4 * wave + j) * 512]);

    for (int it = 0; it < 16; ++it) {
        const int cur = it & 1;
        __syncthreads();                        // buf[cur] staged; buf[cur^1] free
        if (it + 1 < 16) {
            const int ko = (it + 1) * 1024;     // 64 k-elems = 2 units of 512
            #pragma unroll
            for (int j = 0; j < 4; j++) gload16(spA[j] + ko, &Us[cur ^ 1][(4 * wave + j) * 512]);
        }
        #pragma unroll
        for (int kk = 0; kk < 2; kk++) {
            bf16x8 af[4], bf[4];
            #pragma unroll
            for (int i = 0; i < 4; i++)         // B from global (L2 hit), no LDS round-trip
                bf[i] = ldb8(bp[i] + (it * 2 + kk) * 512);
            #pragma unroll
            for (int i = 0; i < 4; i++)         // A from LDS: unit (slab*2+kk), conflict-free
                af[i] = ldb8(&Us[cur][((wy * 4 + i) * 2 + kk) * 512 + lane * 8]);
            #pragma unroll
            for (int mi = 0; mi < 4; mi++)
                #pragma unroll
                for (int ni = 0; ni < 4; ni++)
                    acc[mi][ni] = __builtin_amdgcn_mfma_f32_16x16x32_bf16(af[mi], bf[ni], acc[mi][ni], 0, 0, 0);
        }
    }

    const int gm0 = tm * 128 + wy * 64;
    const int gn0 = tn * 128 + wx * 64;
    #pragma unroll
    for (int ni = 0; ni < 4; ni++) {
        const int n = gn0 + ni * 16 + lm;
        const float bv = bias[n];
        const int which = n >> 10;              // 0=q 1=k 2=v (uniform per block: 128 | 1024)
        const int e = n & 1023;
        const int h = e >> 6, d = e & 63;
        #pragma unroll
        for (int mi = 0; mi < 4; mi++) {
            if (which == 2) {
                const int m0 = gm0 + mi * 16 + quad * 4;
                const int b = m0 >> 11, key0 = m0 & 2047;
                u16x4 pk;
                #pragma unroll
                for (int r = 0; r < 4; r++) pk[r] = f2bf(acc[mi][ni][r] + bv);
                *(u16x4*)&Vb[(b * HH + h) * 131072 + vidx(key0, d)] = pk;
            } else if (which == 1) {
                #pragma unroll
                for (int r = 0; r < 4; r++) {
                    const int m = gm0 + mi * 16 + quad * 4 + r;
                    const int b = m >> 11, s = m & 2047;
                    Kb[(b * HH + h) * 131072 + kidx(s, d)] = f2bf(acc[mi][ni][r] + bv);
                }
            } else {
                #pragma unroll
                for (int r = 0; r < 4; r++) {
                    const int m = gm0 + mi * 16 + quad * 4 + r;
                    const int b = m >> 11, s = m & 2047;
                    Qb[((b * HH + h) * SS + s) * DD + d] = f2bf((acc[mi][ni][r] + bv) * QSCALE);
                }
            }
        }
    }
}

// ---------- 3. causal flash attention: 8 waves pair-split + deferred-PV pipeline (r9-exact) ----------
// PV(kt-1) runs during iteration kt (independent of QK(kt)); P read hides under QK MFMAs.
// ALL LDS buffers selected by uniform INDEX arithmetic on kt (no pointer rotation):
//   K(kt)  in Ks[kt&1]     V(kt) in Vs[kt%3]     P(kt) in Plds[kt&1]
__global__ __launch_bounds__(512) void attn_kernel(
    const u16* __restrict__ Qb, const u16* __restrict__ Kb,
    const u16* __restrict__ Vb, u16* __restrict__ Ob)   // Ob: frag-ordered [4096 x 1024]
{
    __shared__ __align__(16) u16 Ks[2][4096];        // dbuf 64-key K tiles (8 frag-blocks of 1KB)
    __shared__ __align__(16) u16 Vs[3][4096];        // triple-buffered 64-key V tiles
    __shared__ __align__(16) u16 Plds[2][8 * 16 * 72]; // dbuf per-wave P[q][key], rows padded to 72
    const int tid = threadIdx.x;
    const int lane = tid & 63, wave = tid >> 6;      // wave 0..7
    const int lm = lane & 15, quad = lane >> 4;
    const int bh = blockIdx.x & 31;
    const int pr = blockIdx.x >> 5;                  // 0..15
    const int qtA = 31 - pr, qtB = pr;               // paired 64-row q-tiles (uniform work/block)
    const int qt_w = (wave < 4) ? qtA : qtB;         // this wave's q-tile (wave-uniform)
    const int qrow = qt_w * 64 + (wave & 3) * 16;    // this wave's 16 q-rows
    const int b = bh >> 4, h = bh & 15;

    // Q as B-operand: B[n=q][k=d] (scores pre-scaled by QSCALE at QKV epilogue)
    const u16* qbase = Qb + (bh * SS + qrow) * DD;
    const bf16x8 qf0 = ldb8(qbase + lm * DD + quad * 8);
    const bf16x8 qf1 = ldb8(qbase + lm * DD + 32 + quad * 8);

    const u16* ktile = Kb + bh * 131072;             // + kt*4096 per 64-key tile
    const u16* vtile = Vb + bh * 131072;
    const int pw = wave * 1152;                      // per-wave P offset within a P buffer

    BfCast oc; oc.u = (u32x4){0x3F803F80u, 0x3F803F80u, 0x3F803F80u, 0x3F803F80u};
    const bf16x8 ones = oc.b;

    f32x4 oacc[4] = {};                              // O^T[d = dg*16+quad*4+r][q=lm]
    f32x4 lacc = {0.f, 0.f, 0.f, 0.f};               // l[q=lm] in every reg (ones-MFMA)

    const int ktmax = qtA + 1;                       // heavy tile's key range covers both
    {   // prologue: 8 waves stage kt=0 (each wave 1KB of K + 1KB of V)
        gload16(ktile + wave * 512 + lane * 8, &Ks[0][wave * 512]);
        gload16(vtile + wave * 512 + lane * 8, &Vs[0][wave * 512]);
    }
    for (int kt = 0; kt < ktmax; ++kt) {
        const int k0 = kt * 64;
        __syncthreads();                             // tile kt staged; prior-iter LDS reads drained
        if (kt + 1 < ktmax) {                        // prefetch next tile (overlaps compute)
            gload16(ktile + (kt + 1) * 4096 + wave * 512 + lane * 8, &Ks[(kt + 1) & 1][wave * 512]);
            gload16(vtile + (kt + 1) * 4096 + wave * 512 + lane * 8, &Vs[(kt + 1) % 3][wave * 512]);
        }
        const int rb = (kt & 1) ^ 1;                 // P(kt-1) buffer
        const int vb3 = (kt + 2) % 3;                // V(kt-1) buffer ((kt-1)%3)

        if (kt <= qt_w) {                            // wave-uniform: this wave's tile active
            // deferred P(kt-1) read issued early: latency hides under QK MFMAs
            bf16x8 pf0, pf1;
            if (kt > 0) {
                pf0 = ldb8(&Plds[rb][pw + lm * 72 + quad * 8]);
                pf1 = ldb8(&Plds[rb][pw + lm * 72 + 32 + quad * 8]);
            }
            // S^T = K Q^T: A=K-frag (m=key), B=Q (n=q) -> D[key=quad*4+r][q=lm], 4 key groups
            f32x4 s[4];
            #pragma unroll
            for (int g = 0; g < 4; g++) {
                f32x4 z = {0.f, 0.f, 0.f, 0.f};
                z    = __builtin_amdgcn_mfma_f32_16x16x32_bf16(ldb8(&Ks[kt & 1][(g * 2) * 512 + lane * 8]), qf0, z, 0, 0, 0);
                s[g] = __builtin_amdgcn_mfma_f32_16x16x32_bf16(ldb8(&Ks[kt & 1][(g * 2 + 1) * 512 + lane * 8]), qf1, z, 0, 0, 0);
            }
            // deferred PV(kt-1): independent of QK(kt) -> back-to-back MFMA block
            if (kt > 0) {
                lacc = __builtin_amdgcn_mfma_f32_16x16x32_bf16(ones, pf0, lacc, 0, 0, 0);
                lacc = __builtin_amdgcn_mfma_f32_16x16x32_bf16(ones, pf1, lacc, 0, 0, 0);
                #pragma unroll
                for (int dg = 0; dg < 4; dg++) {
                    oacc[dg] = __builtin_amdgcn_mfma_f32_16x16x32_bf16(ldb8(&Vs[vb3][dg * 512 + lane * 8]),       pf0, oacc[dg], 0, 0, 0);
                    oacc[dg] = __builtin_amdgcn_mfma_f32_16x16x32_bf16(ldb8(&Vs[vb3][(4 + dg) * 512 + lane * 8]), pf1, oacc[dg], 0, 0, 0);
                }
            }
            // mask (diagonal tile only), P = exp2(S), pack, write P(kt) to Plds[kt&1]
            if (k0 + 63 > qrow) {                    // causal mask (key > q)
                const int lim = qrow + lm - k0 - quad * 4;
                #pragma unroll
                for (int g = 0; g < 4; g++)
                    #pragma unroll
                    for (int r = 0; r < 4; r++)
                        if (g * 16 + r > lim) s[g][r] = -INFINITY;
            }
            #pragma unroll
            for (int g = 0; g < 4; g++) {
                u32x2 w;
                w[0] = cvtpk(__builtin_amdgcn_exp2f(s[g][0]), __builtin_amdgcn_exp2f(s[g][1]));
                w[1] = cvtpk(__builtin_amdgcn_exp2f(s[g][2]), __builtin_amdgcn_exp2f(s[g][3]));
                *(u32x2*)&Plds[kt & 1][pw + lm * 72 + g * 16 + quad * 4] = w;
            }
        } else if (kt == qt_w + 1) {                 // B-side waves: flush final PV in-loop
            const bf16x8 pf0 = ldb8(&Plds[rb][pw + lm * 72 + quad * 8]);
            const bf16x8 pf1 = ldb8(&Plds[rb][pw + lm * 72 + 32 + quad * 8]);
            lacc = __builtin_amdgcn_mfma_f32_16x16x32_bf16(ones, pf0, lacc, 0, 0, 0);
            lacc = __builtin_amdgcn_mfma_f32_16x16x32_bf16(ones, pf1, lacc, 0, 0, 0);
            #pragma unroll
            for (int dg = 0; dg < 4; dg++) {
                oacc[dg] = __builtin_amdgcn_mfma_f32_16x16x32_bf16(ldb8(&Vs[vb3][dg * 512 + lane * 8]),       pf0, oacc[dg], 0, 0, 0);
                oacc[dg] = __builtin_amdgcn_mfma_f32_16x16x32_bf16(ldb8(&Vs[vb3][(4 + dg) * 512 + lane * 8]), pf1, oacc[dg], 0, 0, 0);
            }
        }
    }
    if (wave < 4) {                                  // A-side waves: flush final PV post-loop
        const int rb = qtA & 1;                      // P(qtA) buffer
        const int vb3 = qtA % 3;                     // V(qtA) buffer (staged at kt=qtA-1, untouched after)
        const bf16x8 pf0 = ldb8(&Plds[rb][pw + lm * 72 + quad * 8]);
        const bf16x8 pf1 = ldb8(&Plds[rb][pw + lm * 72 + 32 + quad * 8]);
        lacc = __builtin_amdgcn_mfma_f32_16x16x32_bf16(ones, pf0, lacc, 0, 0, 0);
        lacc = __builtin_amdgcn_mfma_f32_16x16x32_bf16(ones, pf1, lacc, 0, 0, 0);
        #pragma unroll
        for (int dg = 0; dg < 4; dg++) {
            oacc[dg] = __builtin_amdgcn_mfma_f32_16x16x32_bf16(ldb8(&Vs[vb3][dg * 512 + lane * 8]),       pf0, oacc[dg], 0, 0, 0);
            oacc[dg] = __builtin_amdgcn_mfma_f32_16x16x32_bf16(ldb8(&Vs[vb3][(4 + dg) * 512 + lane * 8]), pf1, oacc[dg], 0, 0, 0);
        }
    }
    // epilogue: O^T/l -> Ob frag-ordered at (m = b*S+qrow+lm, kk = h*64 + dg*16 + quad*4 + r)
    const float inv = 1.0f / lacc[0];
    u16* ob = Ob + (((b * SS + qrow) >> 4) * 32 + h * 2) * 512;
    #pragma unroll
    for (int dg = 0; dg < 4; dg++) {
        u32x2 w;
        w[0] = cvtpk(oacc[dg][0] * inv, oacc[dg][1] * inv);
        w[1] = cvtpk(oacc[dg][2] * inv, oacc[dg][3] * inv);
        *(u32x2*)&ob[(dg >> 1) * 512 + (((dg * 2 + (quad >> 1)) & 3) * 16 + lm) * 8 + (quad & 1) * 4] = w;
    }
}

// ---------- 4. out-proj GEMM (128x128 tile, BK=32, dbuf, frag-ordered) -> fp32 ----------
__global__ __launch_bounds__(256) void gemm_out_kernel(
    const u16* __restrict__ Af,  // attn O frag-ordered [4096 x 1024]
    const u16* __restrict__ Bf,  // W_out^T frag-ordered [1024 x 1024]
    const float* __restrict__ bias,
    float* __restrict__ Out)
{
    __shared__ __align__(16) u16 Us[2][16 * 512];   // 8 A units + 8 B units per buf (16 KB)
    const int lane = threadIdx.x & 63;
    const int wave = threadIdx.x >> 6;
    const int nb = EE / 128;                    // 8
    // XCD-bijective swizzle (grid 256 = 8 x 32) — kept from r11/r12/r13
    const int wg = (blockIdx.x & 7) * 32 + (blockIdx.x >> 3);
    const int tm = wg / nb, tn = wg % nb;
    const int lm = lane & 15, quad = lane >> 4;

    const u16* sp[4];
    #pragma unroll
    for (int j = 0; j < 4; j++) {
        const int idx = 4 * wave + j;
        sp[j] = (idx < 8) ? (Af + (tm * 8 + idx) * UG + lane * 8)
                          : (Bf + (tn * 8 + idx - 8) * UG + lane * 8);
    }
    u16* ld0 = &Us[0][4 * wave * 512];
    u16* ld1 = &Us[1][4 * wave * 512];

    const int wy = wave >> 1, wx = wave & 1;    // wave tile 64x64
    f32x4 acc[4][4] = {};

    #pragma unroll
    for (int j = 0; j < 4; j++) gload16(sp[j], ld0 + j * 512);

    for (int it = 0; it < 32; ++it) {
        const int cur = it & 1;
        __syncthreads();
        if (it + 1 < 32) {
            u16* ld = cur ? ld0 : ld1;
            const int ko = (it + 1) * 512;
            #pragma unroll
            for (int j = 0; j < 4; j++) gload16(sp[j] + ko, ld + j * 512);
        }
        bf16x8 af[4], bf[4];
        #pragma unroll
        for (int i = 0; i < 4; i++) {
            af[i] = ldb8(&Us[cur][(wy * 4 + i) * 512 + lane * 8]);
            bf[i] = ldb8(&Us[cur][(8 + wx * 4 + i) * 512 + lane * 8]);
        }
        #pragma unroll
        for (int mi = 0; mi < 4; mi++)
            #pragma unroll
            for (int ni = 0; ni < 4; ni++)
                acc[mi][ni] = __builtin_amdgcn_mfma_f32_16x16x32_bf16(af[mi], bf[ni], acc[mi][ni], 0, 0, 0);
    }

    const int gm0 = tm * 128 + wy * 64;
    const int gn0 = tn * 128 + wx * 64;
    #pragma unroll
    for (int ni = 0; ni < 4; ni++) {
        const int n = gn0 + ni * 16 + lm;
        const float bv = bias[n];
        #pragma unroll
        for (int mi = 0; mi < 4; mi++)
            #pragma unroll
            for (int r = 0; r < 4; r++)
                Out[(gm0 + mi * 16 + quad * 4 + r) * EE + n] = acc[mi][ni][r] + bv;
    }
}

// ---------- launch ----------
extern "C" void kernel_launch(void* const* d_in, const int* in_sizes, int n_in,
                              void* d_out, int out_size, void* d_ws, size_t ws_size,
                              hipStream_t stream)
{
    const float* x     = (const float*)d_in[0];
    const float* Wqkv  = (const float*)d_in[1];
    const float* bqkv  = (const float*)d_in[2];
    const float* Wout  = (const float*)d_in[3];
    const float* bout  = (const float*)d_in[4];
    float* out = (float*)d_out;

    char* ws = (char*)d_ws;
    u16* xb    = (u16*)(ws + 0);          //  8 MB  x bf16 frag-ordered
    u16* wqkvT = (u16*)(ws + 8388608);    //  6 MB  W_qkv^T bf16 frag-ordered
    u16* woutT = (u16*)(ws + 14680064);   //  2 MB  W_out^T bf16 frag-ordered
    u16* Qb    = (u16*)(ws + 16777216);   //  8 MB  [B,H,S,D] (pre-scaled)
    u16* Kb    = (u16*)(ws + 25165824);   //  8 MB  frag-ordered
    u16* Vb    = (u16*)(ws + 33554432);   //  8 MB  frag-ordered
    u16* Ob    = (u16*)(ws + 41943040);   //  8 MB  frag-ordered
    if (ws_size < 50331648) return;       // need 48 MB

    prep_kernel<<<2048 + 3072 + 1024, 256, 0, stream>>>(x, xb, Wqkv, wqkvT, Wout, woutT);
    gemm_qkv_kernel<<<(BB * SS / 128) * (3 * EE / 128), 256, 0, stream>>>(xb, wqkvT, bqkv, Qb, Kb, Vb);
    attn_kernel<<<BB * HH * (SS / 128), 512, 0, stream>>>(Qb, Kb, Vb, Ob);
    gemm_out_kernel<<<(BB * SS / 128) * (EE / 128), 256, 0, stream>>>(Ob, woutT, bout, out);
}

// Round 16
// 159.605 us; speedup vs baseline: 1.1007x; 1.1007x over previous
//
#include <hip/hip_runtime.h>

typedef unsigned short u16;
typedef __bf16  bf16x8 __attribute__((ext_vector_type(8)));
typedef float   f32x4  __attribute__((ext_vector_type(4)));
typedef unsigned int   u32x2 __attribute__((ext_vector_type(2)));
typedef unsigned int   u32x4 __attribute__((ext_vector_type(4)));
typedef unsigned short u16x4 __attribute__((ext_vector_type(4)));
typedef unsigned short u16x8 __attribute__((ext_vector_type(8)));

#define BB 2
#define HH 16
#define DD 64
#define SS 2048
#define EE 1024

// scale(1/8) * log2(e) folded into Q at the QKV epilogue -> scores are exp2-ready
#define QSCALE 0.1803368801111244f

// ---------- helpers ----------
static __device__ __forceinline__ u16 f2bf(float f) {
    unsigned int u = __float_as_uint(f);
    u += 0x7FFFu + ((u >> 16) & 1u);          // round-to-nearest-even
    return (u16)(u >> 16);
}

// packed f32x2 -> bf16x2 (RNE), 1 VALU op
static __device__ __forceinline__ unsigned int cvtpk(float lo, float hi) {
    unsigned int r;
    asm("v_cvt_pk_bf16_f32 %0, %1, %2" : "=v"(r) : "v"(lo), "v"(hi));
    return r;
}

union BfCast { u32x4 u; bf16x8 b; };
static __device__ __forceinline__ bf16x8 ldb8(const u16* p) {
    BfCast x; x.u = *(const u32x4*)p; return x.b;
}

// async global->LDS, 16B per lane; GLOBAL addr is PER-LANE, LDS dest = wave-uniform base + lane*16
static __device__ __forceinline__ void gload16(const u16* g, u16* l) {
    __builtin_amdgcn_global_load_lds(
        (const __attribute__((address_space(1))) unsigned int*)g,
        (__attribute__((address_space(3))) unsigned int*)l, 16, 0, 0);
}

// universal fragment-order: matrix [M][1024] -> unit = (m>>4)*32 + (k>>5) (1KB),
// within: (((k>>3)&3)*16 + (m&15))*8 + (k&7); MFMA lane reads lane*8 -> conflict-free.
#define UG (32 * 512)    // unit-group stride: one 16-row m-slab (all 32 k-units)
// K (QK A-operand) per bh plane (131072 u16): unit = (s>>4)*2 + (d>>5)
static __device__ __forceinline__ int kidx(int s, int d) {
    return (((s >> 4) * 2 + (d >> 5)) * 512) + ((((d >> 3) & 3) * 16 + (s & 15)) * 8) + (d & 7);
}
// V (PV A-operand, V^T[d][key]): unit = (key>>5)*4 + (d>>4)   [canonical, round-4/6/9 verified]
static __device__ __forceinline__ int vidx(int key, int d) {
    return (((key >> 5) * 4 + (d >> 4)) * 512) + ((((key >> 3) & 3) * 16 + (d & 15)) * 8) + (key & 7);
}

// ---------- 1. fused prep: conv x->frag  |  transpose Wqkv->frag  |  transpose Wout->frag ----------
__global__ __launch_bounds__(256) void prep_kernel(
    const float* __restrict__ x,    u16* __restrict__ xb,
    const float* __restrict__ Wqkv, u16* __restrict__ wqkvT,
    const float* __restrict__ Wout, u16* __restrict__ woutT)
{
    __shared__ float tile[32][33];
    const int bid = blockIdx.x;
    if (bid < 2048) {
        // conv: x [4096][1024] fp32 -> frag-order bf16
        const int t = bid * 256 + threadIdx.x;
        const int u = t >> 6, w = t & 63;
        const int m = (u >> 5) * 16 + (w & 15);
        const int k = (u & 31) * 32 + (w >> 4) * 8;
        const float* p = x + m * 1024 + k;
        const f32x4 a = *(const f32x4*)p;
        const f32x4 b = *(const f32x4*)(p + 4);
        u16x8 o;
        o[0] = f2bf(a[0]); o[1] = f2bf(a[1]); o[2] = f2bf(a[2]); o[3] = f2bf(a[3]);
        o[4] = f2bf(b[0]); o[5] = f2bf(b[1]); o[6] = f2bf(b[2]); o[7] = f2bf(b[3]);
        *(u16x8*)&xb[u * 512 + w * 8] = o;
        return;
    }
    // transpose W[k][n] fp32 -> frag-order bf16 over [n][k]
    const float* in; u16* out; int C, tb;
    if (bid < 2048 + 3072) { in = Wqkv; out = wqkvT; C = 3072; tb = bid - 2048; }
    else                   { in = Wout; out = woutT; C = 1024; tb = bid - 5120; }
    const int tx = threadIdx.x & 31;
    const int ty = threadIdx.x >> 5;          // 0..7
    const int ct = C >> 5;
    const int bc = tb % ct, br = tb / ct;
    const int c0 = bc * 32, r0 = br * 32;     // r=k, c=n
    #pragma unroll
    for (int i = 0; i < 4; i++)
        tile[ty + i * 8][tx] = in[(r0 + ty + i * 8) * C + c0 + tx];
    __syncthreads();
    #pragma unroll
    for (int i = 0; i < 4; i++) {
        const int n = c0 + ty + i * 8;
        out[((n >> 4) * 32 + (r0 >> 5)) * 512 + (((tx >> 3) & 3) * 16 + (n & 15)) * 8 + (tx & 7)]
            = f2bf(tile[tx][ty + i * 8]);
    }
}

// ---------- 2. QKV GEMM (128x128 tile, BK=32, TRIPLE-buffer + counted vmcnt, frag-ordered) ----------
// Natural block order (XCD = tn%8: 3 B-panels/XCD, L2-resident). T4 pipeline: per iteration
// `vmcnt(4); s_barrier` — tile it's loads complete, tile it+1's 4 loads stay IN FLIGHT through
// the barrier (no drain). WAR safe: issue(it+2)->buf[(it-1)%3] happens after the iter-it barrier,
// by which point all waves' iter-(it-1) ds_reads have retired (lgkm-waited before their MFMAs).
__global__ __launch_bounds__(256) void gemm_qkv_kernel(
    const u16* __restrict__ Af,  // x frag-ordered [4096 x 1024]
    const u16* __restrict__ Bf,  // W_qkv^T frag-ordered [3072 x 1024]
    const float* __restrict__ bias,
    u16* __restrict__ Qb, u16* __restrict__ Kb, u16* __restrict__ Vb)
{
    __shared__ __align__(16) u16 Us[3][16 * 512];   // 3 x 16 KB (8 A units + 8 B units per tile)
    const int lane = threadIdx.x & 63;
    const int wave = threadIdx.x >> 6;
    const int nb = 3 * EE / 128;                // 24
    const int tm = blockIdx.x / nb, tn = blockIdx.x % nb;
    const int lm = lane & 15, quad = lane >> 4;

    // staging: wave stages units 4w..4w+3 (A idx 0..7, B idx 8..15); 4 gloads per tile per wave
    const u16* sp[4];
    #pragma unroll
    for (int j = 0; j < 4; j++) {
        const int idx = 4 * wave + j;
        sp[j] = (idx < 8) ? (Af + (tm * 8 + idx) * UG + lane * 8)
                          : (Bf + (tn * 8 + idx - 8) * UG + lane * 8);
    }

    const int wy = wave >> 1, wx = wave & 1;    // wave tile 64x64
    f32x4 acc[4][4] = {};

    // prologue: issue K-tiles 0 and 1
    #pragma unroll
    for (int j = 0; j < 4; j++) gload16(sp[j], &Us[0][(4 * wave + j) * 512]);
    #pragma unroll
    for (int j = 0; j < 4; j++) gload16(sp[j] + 512, &Us[1][(4 * wave + j) * 512]);

    for (int it = 0; it < 32; ++it) {
        const int cur = it % 3;
        // own outstanding after wait <= 4 (= tile it+1's batch) -> tile it's loads landed
        if (it < 31) asm volatile("s_waitcnt vmcnt(4)" ::: "memory");
        else         asm volatile("s_waitcnt vmcnt(0)" ::: "memory");
        __builtin_amdgcn_sched_barrier(0);
        __builtin_amdgcn_s_barrier();           // all waves' tile-it loads landed; it+1 stays in flight

        bf16x8 af[4], bf[4];
        #pragma unroll
        for (int i = 0; i < 4; i++) {           // conflict-free: unit*512 + lane*8
            af[i] = ldb8(&Us[cur][(wy * 4 + i) * 512 + lane * 8]);
            bf[i] = ldb8(&Us[cur][(8 + wx * 4 + i) * 512 + lane * 8]);
        }
        #pragma unroll
        for (int mi = 0; mi < 4; mi++)
            #pragma unroll
            for (int ni = 0; ni < 4; ni++)
                acc[mi][ni] = __builtin_amdgcn_mfma_f32_16x16x32_bf16(af[mi], bf[ni], acc[mi][ni], 0, 0, 0);

        if (it + 2 < 32) {                      // issue tile it+2 into buf (it+2)%3
            const int nxt = (it + 2) % 3;
            const int ko = (it + 2) * 512;
            #pragma unroll
            for (int j = 0; j < 4; j++) gload16(sp[j] + ko, &Us[nxt][(4 * wave + j) * 512]);
        }
    }

    const int gm0 = tm * 128 + wy * 64;
    const int gn0 = tn * 128 + wx * 64;
    #pragma unroll
    for (int ni = 0; ni < 4; ni++) {
        const int n = gn0 + ni * 16 + lm;
        const float bv = bias[n];
        const int which = n >> 10;              // 0=q 1=k 2=v (uniform per block: 128 | 1024)
        const int e = n & 1023;
        const int h = e >> 6, d = e & 63;
        #pragma unroll
        for (int mi = 0; mi < 4; mi++) {
            if (which == 2) {
                const int m0 = gm0 + mi * 16 + quad * 4;
                const int b = m0 >> 11, key0 = m0 & 2047;
                u16x4 pk;
                #pragma unroll
                for (int r = 0; r < 4; r++) pk[r] = f2bf(acc[mi][ni][r] + bv);
                *(u16x4*)&Vb[(b * HH + h) * 131072 + vidx(key0, d)] = pk;
            } else if (which == 1) {
                #pragma unroll
                for (int r = 0; r < 4; r++) {
                    const int m = gm0 + mi * 16 + quad * 4 + r;
                    const int b = m >> 11, s = m & 2047;
                    Kb[(b * HH + h) * 131072 + kidx(s, d)] = f2bf(acc[mi][ni][r] + bv);
                }
            } else {
                #pragma unroll
                for (int r = 0; r < 4; r++) {
                    const int m = gm0 + mi * 16 + quad * 4 + r;
                    const int b = m >> 11, s = m & 2047;
                    Qb[((b * HH + h) * SS + s) * DD + d] = f2bf((acc[mi][ni][r] + bv) * QSCALE);
                }
            }
        }
    }
}

// ---------- 3. causal flash attention: 8 waves pair-split + deferred-PV pipeline (r9-exact) ----------
// PV(kt-1) runs during iteration kt (independent of QK(kt)); P read hides under QK MFMAs.
// ALL LDS buffers selected by uniform INDEX arithmetic on kt (no pointer rotation):
//   K(kt)  in Ks[kt&1]     V(kt) in Vs[kt%3]     P(kt) in Plds[kt&1]
__global__ __launch_bounds__(512) void attn_kernel(
    const u16* __restrict__ Qb, const u16* __restrict__ Kb,
    const u16* __restrict__ Vb, u16* __restrict__ Ob)   // Ob: frag-ordered [4096 x 1024]
{
    __shared__ __align__(16) u16 Ks[2][4096];        // dbuf 64-key K tiles (8 frag-blocks of 1KB)
    __shared__ __align__(16) u16 Vs[3][4096];        // triple-buffered 64-key V tiles
    __shared__ __align__(16) u16 Plds[2][8 * 16 * 72]; // dbuf per-wave P[q][key], rows padded to 72
    const int tid = threadIdx.x;
    const int lane = tid & 63, wave = tid >> 6;      // wave 0..7
    const int lm = lane & 15, quad = lane >> 4;
    const int bh = blockIdx.x & 31;
    const int pr = blockIdx.x >> 5;                  // 0..15
    const int qtA = 31 - pr, qtB = pr;               // paired 64-row q-tiles (uniform work/block)
    const int qt_w = (wave < 4) ? qtA : qtB;         // this wave's q-tile (wave-uniform)
    const int qrow = qt_w * 64 + (wave & 3) * 16;    // this wave's 16 q-rows
    const int b = bh >> 4, h = bh & 15;

    // Q as B-operand: B[n=q][k=d] (scores pre-scaled by QSCALE at QKV epilogue)
    const u16* qbase = Qb + (bh * SS + qrow) * DD;
    const bf16x8 qf0 = ldb8(qbase + lm * DD + quad * 8);
    const bf16x8 qf1 = ldb8(qbase + lm * DD + 32 + quad * 8);

    const u16* ktile = Kb + bh * 131072;             // + kt*4096 per 64-key tile
    const u16* vtile = Vb + bh * 131072;
    const int pw = wave * 1152;                      // per-wave P offset within a P buffer

    BfCast oc; oc.u = (u32x4){0x3F803F80u, 0x3F803F80u, 0x3F803F80u, 0x3F803F80u};
    const bf16x8 ones = oc.b;

    f32x4 oacc[4] = {};                              // O^T[d = dg*16+quad*4+r][q=lm]
    f32x4 lacc = {0.f, 0.f, 0.f, 0.f};               // l[q=lm] in every reg (ones-MFMA)

    const int ktmax = qtA + 1;                       // heavy tile's key range covers both
    {   // prologue: 8 waves stage kt=0 (each wave 1KB of K + 1KB of V)
        gload16(ktile + wave * 512 + lane * 8, &Ks[0][wave * 512]);
        gload16(vtile + wave * 512 + lane * 8, &Vs[0][wave * 512]);
    }
    for (int kt = 0; kt < ktmax; ++kt) {
        const int k0 = kt * 64;
        __syncthreads();                             // tile kt staged; prior-iter LDS reads drained
        if (kt + 1 < ktmax) {                        // prefetch next tile (overlaps compute)
            gload16(ktile + (kt + 1) * 4096 + wave * 512 + lane * 8, &Ks[(kt + 1) & 1][wave * 512]);
            gload16(vtile + (kt + 1) * 4096 + wave * 512 + lane * 8, &Vs[(kt + 1) % 3][wave * 512]);
        }
        const int rb = (kt & 1) ^ 1;                 // P(kt-1) buffer
        const int vb3 = (kt + 2) % 3;                // V(kt-1) buffer ((kt-1)%3)

        if (kt <= qt_w) {                            // wave-uniform: this wave's tile active
            // deferred P(kt-1) read issued early: latency hides under QK MFMAs
            bf16x8 pf0, pf1;
            if (kt > 0) {
                pf0 = ldb8(&Plds[rb][pw + lm * 72 + quad * 8]);
                pf1 = ldb8(&Plds[rb][pw + lm * 72 + 32 + quad * 8]);
            }
            // S^T = K Q^T: A=K-frag (m=key), B=Q (n=q) -> D[key=quad*4+r][q=lm], 4 key groups
            f32x4 s[4];
            #pragma unroll
            for (int g = 0; g < 4; g++) {
                f32x4 z = {0.f, 0.f, 0.f, 0.f};
                z    = __builtin_amdgcn_mfma_f32_16x16x32_bf16(ldb8(&Ks[kt & 1][(g * 2) * 512 + lane * 8]), qf0, z, 0, 0, 0);
                s[g] = __builtin_amdgcn_mfma_f32_16x16x32_bf16(ldb8(&Ks[kt & 1][(g * 2 + 1) * 512 + lane * 8]), qf1, z, 0, 0, 0);
            }
            // deferred PV(kt-1): independent of QK(kt) -> back-to-back MFMA block
            if (kt > 0) {
                lacc = __builtin_amdgcn_mfma_f32_16x16x32_bf16(ones, pf0, lacc, 0, 0, 0);
                lacc = __builtin_amdgcn_mfma_f32_16x16x32_bf16(ones, pf1, lacc, 0, 0, 0);
                #pragma unroll
                for (int dg = 0; dg < 4; dg++) {
                    oacc[dg] = __builtin_amdgcn_mfma_f32_16x16x32_bf16(ldb8(&Vs[vb3][dg * 512 + lane * 8]),       pf0, oacc[dg], 0, 0, 0);
                    oacc[dg] = __builtin_amdgcn_mfma_f32_16x16x32_bf16(ldb8(&Vs[vb3][(4 + dg) * 512 + lane * 8]), pf1, oacc[dg], 0, 0, 0);
                }
            }
            // mask (diagonal tile only), P = exp2(S), pack, write P(kt) to Plds[kt&1]
            if (k0 + 63 > qrow) {                    // causal mask (key > q)
                const int lim = qrow + lm - k0 - quad * 4;
                #pragma unroll
                for (int g = 0; g < 4; g++)
                    #pragma unroll
                    for (int r = 0; r < 4; r++)
                        if (g * 16 + r > lim) s[g][r] = -INFINITY;
            }
            #pragma unroll
            for (int g = 0; g < 4; g++) {
                u32x2 w;
                w[0] = cvtpk(__builtin_amdgcn_exp2f(s[g][0]), __builtin_amdgcn_exp2f(s[g][1]));
                w[1] = cvtpk(__builtin_amdgcn_exp2f(s[g][2]), __builtin_amdgcn_exp2f(s[g][3]));
                *(u32x2*)&Plds[kt & 1][pw + lm * 72 + g * 16 + quad * 4] = w;
            }
        } else if (kt == qt_w + 1) {                 // B-side waves: flush final PV in-loop
            const bf16x8 pf0 = ldb8(&Plds[rb][pw + lm * 72 + quad * 8]);
            const bf16x8 pf1 = ldb8(&Plds[rb][pw + lm * 72 + 32 + quad * 8]);
            lacc = __builtin_amdgcn_mfma_f32_16x16x32_bf16(ones, pf0, lacc, 0, 0, 0);
            lacc = __builtin_amdgcn_mfma_f32_16x16x32_bf16(ones, pf1, lacc, 0, 0, 0);
            #pragma unroll
            for (int dg = 0; dg < 4; dg++) {
                oacc[dg] = __builtin_amdgcn_mfma_f32_16x16x32_bf16(ldb8(&Vs[vb3][dg * 512 + lane * 8]),       pf0, oacc[dg], 0, 0, 0);
                oacc[dg] = __builtin_amdgcn_mfma_f32_16x16x32_bf16(ldb8(&Vs[vb3][(4 + dg) * 512 + lane * 8]), pf1, oacc[dg], 0, 0, 0);
            }
        }
    }
    if (wave < 4) {                                  // A-side waves: flush final PV post-loop
        const int rb = qtA & 1;                      // P(qtA) buffer
        const int vb3 = qtA % 3;                     // V(qtA) buffer (staged at kt=qtA-1, untouched after)
        const bf16x8 pf0 = ldb8(&Plds[rb][pw + lm * 72 + quad * 8]);
        const bf16x8 pf1 = ldb8(&Plds[rb][pw + lm * 72 + 32 + quad * 8]);
        lacc = __builtin_amdgcn_mfma_f32_16x16x32_bf16(ones, pf0, lacc, 0, 0, 0);
        lacc = __builtin_amdgcn_mfma_f32_16x16x32_bf16(ones, pf1, lacc, 0, 0, 0);
        #pragma unroll
        for (int dg = 0; dg < 4; dg++) {
            oacc[dg] = __builtin_amdgcn_mfma_f32_16x16x32_bf16(ldb8(&Vs[vb3][dg * 512 + lane * 8]),       pf0, oacc[dg], 0, 0, 0);
            oacc[dg] = __builtin_amdgcn_mfma_f32_16x16x32_bf16(ldb8(&Vs[vb3][(4 + dg) * 512 + lane * 8]), pf1, oacc[dg], 0, 0, 0);
        }
    }
    // epilogue: O^T/l -> Ob frag-ordered at (m = b*S+qrow+lm, kk = h*64 + dg*16 + quad*4 + r)
    const float inv = 1.0f / lacc[0];
    u16* ob = Ob + (((b * SS + qrow) >> 4) * 32 + h * 2) * 512;
    #pragma unroll
    for (int dg = 0; dg < 4; dg++) {
        u32x2 w;
        w[0] = cvtpk(oacc[dg][0] * inv, oacc[dg][1] * inv);
        w[1] = cvtpk(oacc[dg][2] * inv, oacc[dg][3] * inv);
        *(u32x2*)&ob[(dg >> 1) * 512 + (((dg * 2 + (quad >> 1)) & 3) * 16 + lm) * 8 + (quad & 1) * 4] = w;
    }
}

// ---------- 4. out-proj GEMM (128x128 tile, BK=32, dbuf, frag-ordered) -> fp32 ----------
__global__ __launch_bounds__(256) void gemm_out_kernel(
    const u16* __restrict__ Af,  // attn O frag-ordered [4096 x 1024]
    const u16* __restrict__ Bf,  // W_out^T frag-ordered [1024 x 1024]
    const float* __restrict__ bias,
    float* __restrict__ Out)
{
    __shared__ __align__(16) u16 Us[2][16 * 512];   // 8 A units + 8 B units per buf (16 KB)
    const int lane = threadIdx.x & 63;
    const int wave = threadIdx.x >> 6;
    const int nb = EE / 128;                    // 8
    // XCD-bijective swizzle (grid 256 = 8 x 32)
    const int wg = (blockIdx.x & 7) * 32 + (blockIdx.x >> 3);
    const int tm = wg / nb, tn = wg % nb;
    const int lm = lane & 15, quad = lane >> 4;

    const u16* sp[4];
    #pragma unroll
    for (int j = 0; j < 4; j++) {
        const int idx = 4 * wave + j;
        sp[j] = (idx < 8) ? (Af + (tm * 8 + idx) * UG + lane * 8)
                          : (Bf + (tn * 8 + idx - 8) * UG + lane * 8);
    }
    u16* ld0 = &Us[0][4 * wave * 512];
    u16* ld1 = &Us[1][4 * wave * 512];

    const int wy = wave >> 1, wx = wave & 1;    // wave tile 64x64
    f32x4 acc[4][4] = {};

    #pragma unroll
    for (int j = 0; j < 4; j++) gload16(sp[j], ld0 + j * 512);

    for (int it = 0; it < 32; ++it) {
        const int cur = it & 1;
        __syncthreads();
        if (it + 1 < 32) {
            u16* ld = cur ? ld0 : ld1;
            const int ko = (it + 1) * 512;
            #pragma unroll
            for (int j = 0; j < 4; j++) gload16(sp[j] + ko, ld + j * 512);
        }
        bf16x8 af[4], bf[4];
        #pragma unroll
        for (int i = 0; i < 4; i++) {
            af[i] = ldb8(&Us[cur][(wy * 4 + i) * 512 + lane * 8]);
            bf[i] = ldb8(&Us[cur][(8 + wx * 4 + i) * 512 + lane * 8]);
        }
        #pragma unroll
        for (int mi = 0; mi < 4; mi++)
            #pragma unroll
            for (int ni = 0; ni < 4; ni++)
                acc[mi][ni] = __builtin_amdgcn_mfma_f32_16x16x32_bf16(af[mi], bf[ni], acc[mi][ni], 0, 0, 0);
    }

    const int gm0 = tm * 128 + wy * 64;
    const int gn0 = tn * 128 + wx * 64;
    #pragma unroll
    for (int ni = 0; ni < 4; ni++) {
        const int n = gn0 + ni * 16 + lm;
        const float bv = bias[n];
        #pragma unroll
        for (int mi = 0; mi < 4; mi++)
            #pragma unroll
            for (int r = 0; r < 4; r++)
                Out[(gm0 + mi * 16 + quad * 4 + r) * EE + n] = acc[mi][ni][r] + bv;
    }
}

// ---------- launch ----------
extern "C" void kernel_launch(void* const* d_in, const int* in_sizes, int n_in,
                              void* d_out, int out_size, void* d_ws, size_t ws_size,
                              hipStream_t stream)
{
    const float* x     = (const float*)d_in[0];
    const float* Wqkv  = (const float*)d_in[1];
    const float* bqkv  = (const float*)d_in[2];
    const float* Wout  = (const float*)d_in[3];
    const float* bout  = (const float*)d_in[4];
    float* out = (float*)d_out;

    char* ws = (char*)d_ws;
    u16* xb    = (u16*)(ws + 0);          //  8 MB  x bf16 frag-ordered
    u16* wqkvT = (u16*)(ws + 8388608);    //  6 MB  W_qkv^T bf16 frag-ordered
    u16* woutT = (u16*)(ws + 14680064);   //  2 MB  W_out^T bf16 frag-ordered
    u16* Qb    = (u16*)(ws + 16777216);   //  8 MB  [B,H,S,D] (pre-scaled)
    u16* Kb    = (u16*)(ws + 25165824);   //  8 MB  frag-ordered
    u16* Vb    = (u16*)(ws + 33554432);   //  8 MB  frag-ordered
    u16* Ob    = (u16*)(ws + 41943040);   //  8 MB  frag-ordered
    if (ws_size < 50331648) return;       // need 48 MB

    prep_kernel<<<2048 + 3072 + 1024, 256, 0, stream>>>(x, xb, Wqkv, wqkvT, Wout, woutT);
    gemm_qkv_kernel<<<(BB * SS / 128) * (3 * EE / 128), 256, 0, stream>>>(xb, wqkvT, bqkv, Qb, Kb, Vb);
    attn_kernel<<<BB * HH * (SS / 128), 512, 0, stream>>>(Qb, Kb, Vb, Ob);
    gemm_out_kernel<<<(BB * SS / 128) * (EE / 128), 256, 0, stream>>>(Ob, woutT, bout, out);
}